// Round 15
// baseline (47.962 us; speedup 1.0000x reference)
//
#include <hip/hip_runtime.h>
#include <math.h>

#define NA 400000
#define NM 4
#define NP 512
#define ND 32
#define SQF 1.6986437f              /* sqrt(2*log2(e)) folded into BOTH operand scalings */
#define NBH 391                     /* ceil(NA/1024) hist/scatter windows */
#define GTPB 512                    /* gpr threads (8 waves) */
#define NBLK 1024                   /* gpr grid: 4 blocks/CU (36 KiB LDS), 2048 waves/model */
#define WPM ((NBLK / NM) * 8)       /* 2048 waves per model */
#define ACUT 60.0f                  /* skip exp when 16x16 tile all < 2^-60; folded into beta */

typedef __attribute__((ext_vector_type(8))) _Float16 f16x8;
typedef __attribute__((ext_vector_type(4))) float f32x4;

/* ---- workspace layout (bytes) ---- */
#define WS_ZH   0                   /* ushort[NM][32][512] = 131072  z fp16 frags (LDS-staged) */
#define WS_AZY  131072              /* float[NM*512] = 8192   (-0.5*||zhat||^2, p-order) */
#define WS_BET  139264              /* float[NM*512] = 8192   (alpha * 2^-60, p-order)   */
#define WS_ISL  147456              /* float[NM*32]  = 512    (exp(-ls/2)*SQF)           */
#define WS_PART 147968              /* int[NBH][4] = 6256 window histogram partials      */
#define WS_CNT  154224              /* int[4] model totals                               */
#define WS_BKT  154240              /* int[NA] = 1.6 MB                                  */

// ---------------- K1: Z-prep (blocks 0..3) + window histogram (blocks 4..) ----------------
__global__ void prep_hist_kernel(const float* __restrict__ Z,
                                 const float* __restrict__ alpha,
                                 const float* __restrict__ lls,
                                 const int* __restrict__ el,
                                 unsigned short* __restrict__ zh_w,
                                 float* __restrict__ azy,
                                 float* __restrict__ bet,
                                 float* __restrict__ isl,
                                 int* __restrict__ part)
{
    __shared__ float isl_s[ND];
    __shared__ int h[16][NM];
    int tid = threadIdx.x;
    if (blockIdx.x < NM) {
        int m = blockIdx.x;
        if (tid < ND) {
            float v = expf(-0.5f * lls[m * ND + tid]) * SQF;
            isl_s[tid] = v;
            isl[m * ND + tid] = v;
        }
        __syncthreads();
        for (int p = tid; p < NP; p += blockDim.x) {
            const float* zp = Z + (size_t)(m * NP + p) * ND;
            int t = p >> 4, pl = p & 15;
            size_t fb = (size_t)(m * 32 + t) * 512;
            float z2 = 0.f;
#pragma unroll
            for (int d = 0; d < ND; ++d) {
                float zs = zp[d] * isl_s[d];
                _Float16 zh = (_Float16)zs;          // RNE single fp16
                float zr = (float)zh;                // reconstructed value actually used
                z2 = fmaf(zr, zr, z2);               // norm consistent with MFMA operand
                int lane = pl + 16 * (d >> 3), j = d & 7;    // A-frag order
                zh_w[fb + lane * 8 + j] = __builtin_bit_cast(unsigned short, zh);
            }
            azy[m * NP + p] = -0.5f * z2;
            bet[m * NP + p] = alpha[m * NP + p] * 8.673617379884035e-19f;  // * 2^-60 exact
        }
    } else {
        int wnd = blockIdx.x - NM;
        int wv = tid >> 6, lane = tid & 63;
        int i = wnd * 1024 + tid;
        int e = (i < NA) ? el[i] : -1;
#pragma unroll
        for (int mm = 0; mm < NM; ++mm) {
            unsigned long long b = __ballot(e == mm);
            if (lane == 0) h[wv][mm] = __popcll(b);
        }
        __syncthreads();
        if (tid < NM) {
            int s = 0;
#pragma unroll
            for (int k = 0; k < 16; ++k) s += h[k][tid];
            part[wnd * 4 + tid] = s;
        }
    }
}

// ---------------- K2: scatter with on-the-fly prefix (deterministic, atomic-free) ----------------
__global__ void scatter_kernel(const int* __restrict__ el,
                               const int* __restrict__ part,
                               int* __restrict__ cnt,
                               int* __restrict__ bucket)
{
    __shared__ int wcnt_s[16][NM];
    __shared__ int wvoff_s[16][NM];
    __shared__ int gbase_s[NM];
    __shared__ int tot_s[NM];
    __shared__ int bw_s[NM];
    int b = blockIdx.x, tid = threadIdx.x;
    int wv = tid >> 6, lane = tid & 63;
    int i = b * 1024 + tid;
    int e = (i < NA) ? el[i] : -1;
    unsigned long long lt = (1ULL << lane) - 1ULL;
    int myrank = 0;
#pragma unroll
    for (int mm = 0; mm < NM; ++mm) {
        unsigned long long bl = __ballot(e == mm);
        if (e == mm) myrank = __popcll(bl & lt);
        if (lane == 0) wcnt_s[wv][mm] = __popcll(bl);
    }
    if (wv == 0) {                               // totals + exclusive "below" from partials
        int t0 = 0, t1 = 0, t2 = 0, t3 = 0, b0 = 0, b1 = 0, b2 = 0, b3 = 0;
        for (int w2 = lane; w2 < NBH; w2 += 64) {
            int4 pv = ((const int4*)part)[w2];
            t0 += pv.x; t1 += pv.y; t2 += pv.z; t3 += pv.w;
            if (w2 < b) { b0 += pv.x; b1 += pv.y; b2 += pv.z; b3 += pv.w; }
        }
#pragma unroll
        for (int s = 1; s < 64; s <<= 1) {
            t0 += __shfl_xor(t0, s); t1 += __shfl_xor(t1, s);
            t2 += __shfl_xor(t2, s); t3 += __shfl_xor(t3, s);
            b0 += __shfl_xor(b0, s); b1 += __shfl_xor(b1, s);
            b2 += __shfl_xor(b2, s); b3 += __shfl_xor(b3, s);
        }
        if (lane == 0) {
            tot_s[0] = t0; tot_s[1] = t1; tot_s[2] = t2; tot_s[3] = t3;
            bw_s[0] = b0; bw_s[1] = b1; bw_s[2] = b2; bw_s[3] = b3;
        }
    }
    __syncthreads();
    if (tid < NM) {
        int g = bw_s[tid];
        for (int mm = 0; mm < NM; ++mm) if (mm < tid) g += tot_s[mm];
        gbase_s[tid] = g;
        int run = 0;
#pragma unroll
        for (int k = 0; k < 16; ++k) { wvoff_s[k][tid] = run; run += wcnt_s[k][tid]; }
        if (b == 0) cnt[tid] = tot_s[tid];       // replay-safe (rewritten every call)
    }
    __syncthreads();
    if (e >= 0) bucket[gbase_s[e] + wvoff_s[wv][e] + myrank] = i;
}

// ---------------- K3: nt-outer loop — next quarter's gather hides under this quarter's MFMAs ----------------
__global__ __launch_bounds__(GTPB, 4)
void gpr_kernel(const float* __restrict__ x,
                const int* __restrict__ bucket,
                const unsigned short* __restrict__ zh_w,
                const float* __restrict__ azy_w,
                const float* __restrict__ bet_w,
                const float* __restrict__ isl_w,
                const int* __restrict__ cnt_w,
                float* __restrict__ out)
{
    __shared__ __align__(16) unsigned short zf[32][512];   // 32 KiB (z fp16 fragments)
    __shared__ __align__(16) float azy_s[NP];              // 2 KiB
    __shared__ __align__(16) float bet_s[NP];              // 2 KiB

    int m = blockIdx.x & 3;
    int tid = threadIdx.x;
    int c0 = cnt_w[0], c1 = cnt_w[1], c2 = cnt_w[2], c3 = cnt_w[3];
    int c    = (m == 0) ? c0 : (m == 1) ? c1 : (m == 2) ? c2 : c3;
    int base = (m == 0) ? 0 : (m == 1) ? c0 : (m == 2) ? c0 + c1 : c0 + c1 + c2;

    int wv = tid >> 6, lane = tid & 63;
    int lg = lane >> 4, ll = lane & 15;
    int k0 = lg * 8;
    int wm = (blockIdx.x >> 2) * 8 + wv;         // wave id within model, [0, WPM)

    const float4* wp = (const float4*)(isl_w + m * ND + k0);
    float4 w0 = wp[0], w1 = wp[1];

    {   // stage z fragments (32 KiB linear) + azy + beta
        const int4* zg = (const int4*)(zh_w + (size_t)m * 16384);
        int4* zs = (int4*)&zf[0][0];
#pragma unroll
        for (int i = 0; i < 4; ++i) zs[tid + i * GTPB] = zg[tid + i * GTPB];
        if (tid < 128)
            ((float4*)azy_s)[tid] = ((const float4*)(azy_w + m * NP))[tid];
        else if (tid < 256)
            ((float4*)bet_s)[tid - 128] = ((const float4*)(bet_w + m * NP))[tid - 128];
    }

    // first quarter-strip's raw gather BEFORE the barrier (hides under staging)
    float4 ra, rb;
    bool active = (wm * 64 < c);
    if (active) {
        int j = wm * 64 + ll;                    // nt = 0
        int n = bucket[base + ((j < c) ? j : (c - 1))];
        const float4* xp = (const float4*)(x + (size_t)n * ND + k0);
        ra = xp[0]; rb = xp[1];
    }

    __syncthreads();                             // only barrier

    for (int s = wm; s * 64 < c; s += WPM) {     // exactly 1 iter in practice
        int wbase = s * 64;
        if (s != wm) {                           // correctness path only (c > 131072)
            int j = wbase + ll;
            int n = bucket[base + ((j < c) ? j : (c - 1))];
            const float4* xp = (const float4*)(x + (size_t)n * ND + k0);
            ra = xp[0]; rb = xp[1];
        }

        for (int nt = 0; nt < 4; ++nt) {
            // ---- build this quarter's B fragment from held raws ----
            float xs[8] = {ra.x * w0.x, ra.y * w0.y, ra.z * w0.z, ra.w * w0.w,
                           rb.x * w1.x, rb.y * w1.y, rb.z * w1.z, rb.w * w1.w};
            f16x8 B;
            float s2 = 0.f;
#pragma unroll
            for (int i = 0; i < 8; ++i) {
                _Float16 xh = (_Float16)xs[i];   // RNE
                B[i] = xh;
                float xr = (float)xh;            // reconstructed: norm consistent w/ operand
                s2 = fmaf(xr, xr, s2);
            }
            s2 += __shfl_xor(s2, 16);
            s2 += __shfl_xor(s2, 32);
            float x2lc = 0.5f * s2 - ACUT;       // skip threshold; ACUT folded into beta

            // ---- issue NEXT quarter's scattered loads; inner loop below covers latency ----
            if (nt < 3) {
                int j = wbase + (nt + 1) * 16 + ll;
                int n = bucket[base + ((j < c) ? j : (c - 1))];
                const float4* xp = (const float4*)(x + (size_t)n * ND + k0);
                ra = xp[0]; rb = xp[1];
            }

            // ---- 32-tile inner loop, rotated LDS prefetch ----
            float acc = 0.f;
            f16x8 Ah = *(const f16x8*)&zf[0][lane * 8];
            float4 di = *(const float4*)&azy_s[4 * lg];
            float4 bi = *(const float4*)&bet_s[4 * lg];

#pragma unroll 2
            for (int t = 0; t < 32; ++t) {
                f16x8 AhC = Ah;
                f32x4 dinit = __builtin_bit_cast(f32x4, di);
                float4 be4 = bi;
                int tn = (t + 1) & 31;           // wraps on last iter (value unused)
                Ah = *(const f16x8*)&zf[tn][lane * 8];
                di = *(const float4*)&azy_s[tn * 16 + 4 * lg];
                bi = *(const float4*)&bet_s[tn * 16 + 4 * lg];

                f32x4 d = __builtin_amdgcn_mfma_f32_16x16x32_f16(AhC, B, dinit, 0, 0, 0);
                float mx = fmaxf(fmaxf(d[0], d[1]), fmaxf(d[2], d[3]));
                if (__any(mx >= x2lc)) {         // exact per-pair bound, ~74% skip
                    acc = fmaf(be4.x, __builtin_amdgcn_exp2f(d[0] - x2lc), acc);
                    acc = fmaf(be4.y, __builtin_amdgcn_exp2f(d[1] - x2lc), acc);
                    acc = fmaf(be4.z, __builtin_amdgcn_exp2f(d[2] - x2lc), acc);
                    acc = fmaf(be4.w, __builtin_amdgcn_exp2f(d[3] - x2lc), acc);
                }
            }

            // ---- reduce + store this quarter's 16 outputs ----
            float v = acc;
            v += __shfl_xor(v, 16);
            v += __shfl_xor(v, 32);
            if (lane < 16) {
                int j = wbase + nt * 16 + lane;
                if (j < c) out[bucket[base + j]] = v;
            }
        }
    }
}

// ---------------- launch: 3 dispatches, no memsets, no atomics ----------------
extern "C" void kernel_launch(void* const* d_in, const int* in_sizes, int n_in,
                              void* d_out, int out_size, void* d_ws, size_t ws_size,
                              hipStream_t stream)
{
    const int*   element    = (const int*)d_in[0];
    const float* x          = (const float*)d_in[1];
    const float* inducing_x = (const float*)d_in[2];
    const float* alpha      = (const float*)d_in[3];
    const float* log_ls     = (const float*)d_in[4];
    float* out = (float*)d_out;

    char* ws = (char*)d_ws;
    unsigned short* zh = (unsigned short*)(ws + WS_ZH);
    float* azy  = (float*)(ws + WS_AZY);
    float* bet  = (float*)(ws + WS_BET);
    float* isl  = (float*)(ws + WS_ISL);
    int*   part = (int*)(ws + WS_PART);
    int*   cnt  = (int*)(ws + WS_CNT);
    int*   bkt  = (int*)(ws + WS_BKT);

    (void)in_sizes; (void)n_in; (void)out_size; (void)ws_size;

    prep_hist_kernel<<<NM + NBH, 1024, 0, stream>>>(inducing_x, alpha, log_ls, element,
                                                    zh, azy, bet, isl, part);
    scatter_kernel<<<NBH, 1024, 0, stream>>>(element, part, cnt, bkt);
    gpr_kernel<<<NBLK, GTPB, 0, stream>>>(x, bkt, zh, azy, bet, isl, cnt, out);
}

// Round 16
// 43.120 us; speedup vs baseline: 1.1123x; 1.1123x over previous
//
#include <hip/hip_runtime.h>
#include <math.h>

#define NA 400000
#define NM 4
#define NP 512
#define ND 32
#define SQF 1.6986437f              /* sqrt(2*log2(e)) folded into BOTH operand scalings */
#define NBH 391                     /* ceil(NA/1024) hist/scatter windows */
#define GTPB 512                    /* gpr threads (8 waves) */
#define NBLK 1024                   /* gpr grid: 4 blocks/CU (36 KiB LDS), 2048 waves/model */
#define WPM ((NBLK / NM) * 8)       /* 2048 waves per model */
#define ACUT 60.0f                  /* skip exp when 16x16 tile all < 2^-60; folded into beta */

typedef __attribute__((ext_vector_type(8))) _Float16 f16x8;
typedef __attribute__((ext_vector_type(4))) float f32x4;

/* ---- workspace layout (bytes) ---- */
#define WS_ZH   0                   /* ushort[NM][32][512] = 131072  z fp16 frags (LDS-staged) */
#define WS_AZY  131072              /* float[NM*512] = 8192   (-0.5*||zhat||^2, p-order) */
#define WS_BET  139264              /* float[NM*512] = 8192   (alpha * 2^-60, p-order)   */
#define WS_ISL  147456              /* float[NM*32]  = 512    (exp(-ls/2)*SQF)           */
#define WS_PART 147968              /* int[NBH][4] = 6256 window histogram partials      */
#define WS_CNT  154224              /* int[4] model totals                               */
#define WS_BKT  154240              /* int[NA] = 1.6 MB                                  */

// ---------------- K1: Z-prep (blocks 0..3) + window histogram (blocks 4..) ----------------
__global__ void prep_hist_kernel(const float* __restrict__ Z,
                                 const float* __restrict__ alpha,
                                 const float* __restrict__ lls,
                                 const int* __restrict__ el,
                                 unsigned short* __restrict__ zh_w,
                                 float* __restrict__ azy,
                                 float* __restrict__ bet,
                                 float* __restrict__ isl,
                                 int* __restrict__ part)
{
    __shared__ float isl_s[ND];
    __shared__ int h[16][NM];
    int tid = threadIdx.x;
    if (blockIdx.x < NM) {
        int m = blockIdx.x;
        if (tid < ND) {
            float v = expf(-0.5f * lls[m * ND + tid]) * SQF;
            isl_s[tid] = v;
            isl[m * ND + tid] = v;
        }
        __syncthreads();
        for (int p = tid; p < NP; p += blockDim.x) {
            const float* zp = Z + (size_t)(m * NP + p) * ND;
            int t = p >> 4, pl = p & 15;
            size_t fb = (size_t)(m * 32 + t) * 512;
            float z2 = 0.f;
#pragma unroll
            for (int d = 0; d < ND; ++d) {
                float zs = zp[d] * isl_s[d];
                _Float16 zh = (_Float16)zs;          // RNE single fp16
                float zr = (float)zh;                // reconstructed value actually used
                z2 = fmaf(zr, zr, z2);               // norm consistent with MFMA operand
                int lane = pl + 16 * (d >> 3), j = d & 7;    // A-frag order
                zh_w[fb + lane * 8 + j] = __builtin_bit_cast(unsigned short, zh);
            }
            azy[m * NP + p] = -0.5f * z2;
            bet[m * NP + p] = alpha[m * NP + p] * 8.673617379884035e-19f;  // * 2^-60 exact
        }
    } else {
        int wnd = blockIdx.x - NM;
        int wv = tid >> 6, lane = tid & 63;
        int i = wnd * 1024 + tid;
        int e = (i < NA) ? el[i] : -1;
#pragma unroll
        for (int mm = 0; mm < NM; ++mm) {
            unsigned long long b = __ballot(e == mm);
            if (lane == 0) h[wv][mm] = __popcll(b);
        }
        __syncthreads();
        if (tid < NM) {
            int s = 0;
#pragma unroll
            for (int k = 0; k < 16; ++k) s += h[k][tid];
            part[wnd * 4 + tid] = s;
        }
    }
}

// ---------------- K2: scatter with on-the-fly prefix (deterministic, atomic-free) ----------------
__global__ void scatter_kernel(const int* __restrict__ el,
                               const int* __restrict__ part,
                               int* __restrict__ cnt,
                               int* __restrict__ bucket)
{
    __shared__ int wcnt_s[16][NM];
    __shared__ int wvoff_s[16][NM];
    __shared__ int gbase_s[NM];
    __shared__ int tot_s[NM];
    __shared__ int bw_s[NM];
    int b = blockIdx.x, tid = threadIdx.x;
    int wv = tid >> 6, lane = tid & 63;
    int i = b * 1024 + tid;
    int e = (i < NA) ? el[i] : -1;
    unsigned long long lt = (1ULL << lane) - 1ULL;
    int myrank = 0;
#pragma unroll
    for (int mm = 0; mm < NM; ++mm) {
        unsigned long long bl = __ballot(e == mm);
        if (e == mm) myrank = __popcll(bl & lt);
        if (lane == 0) wcnt_s[wv][mm] = __popcll(bl);
    }
    if (wv == 0) {                               // totals + exclusive "below" from partials
        int t0 = 0, t1 = 0, t2 = 0, t3 = 0, b0 = 0, b1 = 0, b2 = 0, b3 = 0;
        for (int w2 = lane; w2 < NBH; w2 += 64) {
            int4 pv = ((const int4*)part)[w2];
            t0 += pv.x; t1 += pv.y; t2 += pv.z; t3 += pv.w;
            if (w2 < b) { b0 += pv.x; b1 += pv.y; b2 += pv.z; b3 += pv.w; }
        }
#pragma unroll
        for (int s = 1; s < 64; s <<= 1) {
            t0 += __shfl_xor(t0, s); t1 += __shfl_xor(t1, s);
            t2 += __shfl_xor(t2, s); t3 += __shfl_xor(t3, s);
            b0 += __shfl_xor(b0, s); b1 += __shfl_xor(b1, s);
            b2 += __shfl_xor(b2, s); b3 += __shfl_xor(b3, s);
        }
        if (lane == 0) {
            tot_s[0] = t0; tot_s[1] = t1; tot_s[2] = t2; tot_s[3] = t3;
            bw_s[0] = b0; bw_s[1] = b1; bw_s[2] = b2; bw_s[3] = b3;
        }
    }
    __syncthreads();
    if (tid < NM) {
        int g = bw_s[tid];
        for (int mm = 0; mm < NM; ++mm) if (mm < tid) g += tot_s[mm];
        gbase_s[tid] = g;
        int run = 0;
#pragma unroll
        for (int k = 0; k < 16; ++k) { wvoff_s[k][tid] = run; run += wcnt_s[k][tid]; }
        if (b == 0) cnt[tid] = tot_s[tid];       // replay-safe (rewritten every call)
    }
    __syncthreads();
    if (e >= 0) bucket[gbase_s[e] + wvoff_s[wv][e] + myrank] = i;
}

// ---------------- frag build: gather 64 atoms -> 4 fp16 B-fragments ----------------
static __device__ __forceinline__ void build_frags(
    const float* __restrict__ x, const int* __restrict__ bucket,
    int base, int c, int wbase, int ll, int k0, float4 w0, float4 w1,
    f16x8* Bh, float* x2lc)
{
#pragma unroll
    for (int nt = 0; nt < 4; ++nt) {
        int j = wbase + nt * 16 + ll;
        int n = bucket[base + ((j < c) ? j : (c - 1))];
        const float4* xp = (const float4*)(x + (size_t)n * ND + k0);
        float4 a = xp[0], b = xp[1];
        float xs[8] = {a.x * w0.x, a.y * w0.y, a.z * w0.z, a.w * w0.w,
                       b.x * w1.x, b.y * w1.y, b.z * w1.z, b.w * w1.w};
        float s2 = 0.f;
#pragma unroll
        for (int i = 0; i < 8; ++i) {
            _Float16 xh = (_Float16)xs[i];       // RNE
            Bh[nt][i] = xh;
            float xr = (float)xh;                // reconstructed: norm consistent w/ operand
            s2 = fmaf(xr, xr, s2);
        }
        s2 += __shfl_xor(s2, 16);
        s2 += __shfl_xor(s2, 32);
        x2lc[nt] = 0.5f * s2 - ACUT;             // skip threshold; ACUT folded into beta
    }
}

// ---------------- K3: r14 structure; bet read only on the taken exp path ----------------
__global__ __launch_bounds__(GTPB, 4)
void gpr_kernel(const float* __restrict__ x,
                const int* __restrict__ bucket,
                const unsigned short* __restrict__ zh_w,
                const float* __restrict__ azy_w,
                const float* __restrict__ bet_w,
                const float* __restrict__ isl_w,
                const int* __restrict__ cnt_w,
                float* __restrict__ out)
{
    __shared__ __align__(16) unsigned short zf[32][512];   // 32 KiB (z fp16 fragments)
    __shared__ __align__(16) float azy_s[NP];              // 2 KiB
    __shared__ __align__(16) float bet_s[NP];              // 2 KiB

    int m = blockIdx.x & 3;
    int tid = threadIdx.x;
    int c0 = cnt_w[0], c1 = cnt_w[1], c2 = cnt_w[2], c3 = cnt_w[3];
    int c    = (m == 0) ? c0 : (m == 1) ? c1 : (m == 2) ? c2 : c3;
    int base = (m == 0) ? 0 : (m == 1) ? c0 : (m == 2) ? c0 + c1 : c0 + c1 + c2;

    int wv = tid >> 6, lane = tid & 63;
    int lg = lane >> 4, ll = lane & 15;
    int k0 = lg * 8;
    int wm = (blockIdx.x >> 2) * 8 + wv;         // wave id within model, [0, WPM)

    const float4* wp = (const float4*)(isl_w + m * ND + k0);
    float4 w0 = wp[0], w1 = wp[1];

    {   // stage z fragments (32 KiB linear) + azy + beta
        const int4* zg = (const int4*)(zh_w + (size_t)m * 16384);
        int4* zs = (int4*)&zf[0][0];
#pragma unroll
        for (int i = 0; i < 4; ++i) zs[tid + i * GTPB] = zg[tid + i * GTPB];
        if (tid < 128)
            ((float4*)azy_s)[tid] = ((const float4*)(azy_w + m * NP))[tid];
        else if (tid < 256)
            ((float4*)bet_s)[tid - 128] = ((const float4*)(bet_w + m * NP))[tid - 128];
    }

    // first strip's gather + frag build BEFORE the barrier
    f16x8 Bh[4];
    float x2lc[4];
    bool active = (wm * 64 < c);
    if (active)
        build_frags(x, bucket, base, c, wm * 64, ll, k0, w0, w1, Bh, x2lc);

    __syncthreads();                             // only barrier

    for (int s = wm; s * 64 < c; s += WPM) {     // <=1 iter in practice
        int wbase = s * 64;
        if (s != wm)                             // correctness path only (c > 131072)
            build_frags(x, bucket, base, c, wbase, ll, k0, w0, w1, Bh, x2lc);

        float acc[4] = {0.f, 0.f, 0.f, 0.f};

        // rotated prefetch prologue (all LDS; bet NOT rotated — read only when needed)
        f16x8 Ah = *(const f16x8*)&zf[0][lane * 8];
        float4 di = *(const float4*)&azy_s[4 * lg];

#pragma unroll 2
        for (int t = 0; t < 32; ++t) {
            f16x8 AhC = Ah;
            f32x4 dinit = __builtin_bit_cast(f32x4, di);
            int tn = (t + 1) & 31;               // wraps on last iter (value unused)
            Ah = *(const f16x8*)&zf[tn][lane * 8];
            di = *(const float4*)&azy_s[tn * 16 + 4 * lg];

            f32x4 dd[4];
            __builtin_amdgcn_s_setprio(1);
#pragma unroll
            for (int nt = 0; nt < 4; ++nt)       // 4 independent MFMAs back-to-back
                dd[nt] = __builtin_amdgcn_mfma_f32_16x16x32_f16(AhC, Bh[nt], dinit, 0, 0, 0);
            __builtin_amdgcn_s_setprio(0);

#pragma unroll
            for (int nt = 0; nt < 4; ++nt) {     // single drain point, branchy tail after
                f32x4 d = dd[nt];
                float mx = fmaxf(fmaxf(d[0], d[1]), fmaxf(d[2], d[3]));
                if (__any(mx >= x2lc[nt])) {     // exact per-pair bound, ~74% skip
                    float4 be4 = *(const float4*)&bet_s[t * 16 + 4 * lg];  // read only here
                    float xl = x2lc[nt];
                    acc[nt] = fmaf(be4.x, __builtin_amdgcn_exp2f(d[0] - xl), acc[nt]);
                    acc[nt] = fmaf(be4.y, __builtin_amdgcn_exp2f(d[1] - xl), acc[nt]);
                    acc[nt] = fmaf(be4.z, __builtin_amdgcn_exp2f(d[2] - xl), acc[nt]);
                    acc[nt] = fmaf(be4.w, __builtin_amdgcn_exp2f(d[3] - xl), acc[nt]);
                }
            }
        }

#pragma unroll
        for (int nt = 0; nt < 4; ++nt) {
            float v = acc[nt];
            v += __shfl_xor(v, 16);
            v += __shfl_xor(v, 32);
            if (lane < 16) {
                int j = wbase + nt * 16 + lane;
                if (j < c) out[bucket[base + j]] = v;
            }
        }
    }
}

// ---------------- launch: 3 dispatches, no memsets, no atomics ----------------
extern "C" void kernel_launch(void* const* d_in, const int* in_sizes, int n_in,
                              void* d_out, int out_size, void* d_ws, size_t ws_size,
                              hipStream_t stream)
{
    const int*   element    = (const int*)d_in[0];
    const float* x          = (const float*)d_in[1];
    const float* inducing_x = (const float*)d_in[2];
    const float* alpha      = (const float*)d_in[3];
    const float* log_ls     = (const float*)d_in[4];
    float* out = (float*)d_out;

    char* ws = (char*)d_ws;
    unsigned short* zh = (unsigned short*)(ws + WS_ZH);
    float* azy  = (float*)(ws + WS_AZY);
    float* bet  = (float*)(ws + WS_BET);
    float* isl  = (float*)(ws + WS_ISL);
    int*   part = (int*)(ws + WS_PART);
    int*   cnt  = (int*)(ws + WS_CNT);
    int*   bkt  = (int*)(ws + WS_BKT);

    (void)in_sizes; (void)n_in; (void)out_size; (void)ws_size;

    prep_hist_kernel<<<NM + NBH, 1024, 0, stream>>>(inducing_x, alpha, log_ls, element,
                                                    zh, azy, bet, isl, part);
    scatter_kernel<<<NBH, 1024, 0, stream>>>(element, part, cnt, bkt);
    gpr_kernel<<<NBLK, GTPB, 0, stream>>>(x, bkt, zh, azy, bet, isl, cnt, out);
}